// Round 7
// baseline (212.534 us; speedup 1.0000x reference)
//
#include <hip/hip_runtime.h>
#include <hip/hip_bf16.h>
#include <math.h>

#define B_ 32
#define S_ 64
#define T_ 256
#define L_ 8
#define D_ 128
#define H_ 128

typedef __attribute__((ext_vector_type(8))) short short8;
typedef __attribute__((ext_vector_type(4))) short short4v;
typedef __attribute__((ext_vector_type(4))) float float4v;

__device__ __forceinline__ short f2bf(float x) {
  __hip_bfloat16 h = __float2bfloat16(x);
  return *reinterpret_cast<short*>(&h);
}

// ---------------------------------------------------------------------------
// Stage A (+prep merged): blocks 0-7 run the Toeplitz-Schur Cholesky (one
// wave per latent l, 256-step serial chain, LDS column panel flushed as
// coalesced rows). Blocks 8-71 convert weights:
//   W1T[c][l] (c = h-col, unpermuted)
//   W2Tp[c][sc] where c = nt*16+n <-> d = n*8+nt (epilogue X-vectorization)
//   and sc is the h-interleave perm: h = 32w+16p+nn -> sc = 32w+2nn+p
//   (lets decode pack both per-lane h-values into one b32 LDS write).
// ---------------------------------------------------------------------------
__global__ __launch_bounds__(64) void k_chol_prep(
    const float* __restrict__ times, const float* __restrict__ log_taus,
    __hip_bfloat16* __restrict__ Lcbf_,
    const float* __restrict__ W1, const float* __restrict__ W2,
    __hip_bfloat16* __restrict__ W1T, __hip_bfloat16* __restrict__ W2Tp)
{
  __shared__ short panel[256][68];
  const int bi = blockIdx.x;
  const int j = threadIdx.x;

  if (bi >= 8) {
    // ---- prep path: 64 blocks x 64 threads ----
    const int base = (bi - 8) * 64 + j;          // 0..4095
    // W2Tp: 16384 elements, 4 per thread
    for (int idx = base; idx < H_ * D_; idx += 4096) {
      const int c = idx & 127, sc = 0, dummy = 0; (void)sc; (void)dummy;
      const int scc = idx >> 7;                  // iterate [c][sc]? no: idx = sc*128+c
      // use idx = sc*128 + c layout for coalescing on W2Tp? W2Tp is [c][sc].
      // simpler: c = idx>>7, sc = idx&127 (contiguous writes per c-row)
      const int cc = idx >> 7, s = idx & 127;
      (void)scc; (void)c;
      const int h = ((s >> 5) << 5) + ((s & 1) << 4) + ((s & 31) >> 1);
      const int n = cc & 15, nt = cc >> 4;
      const int d = n * 8 + nt;
      W2Tp[(size_t)cc * H_ + s] = __float2bfloat16(W2[(size_t)h * D_ + d]);
    }
    // W1T: 1024 elements
    for (int idx = base; idx < L_ * H_; idx += 4096) {
      const int li = idx >> 7, h = idx & 127;
      W1T[(size_t)h * L_ + li] = __float2bfloat16(W1[idx]);
    }
    return;
  }

  const int l = bi;
  short* Lbf = (short*)Lcbf_ + (size_t)l * T_ * T_;

  const float tau = expf(log_taus[l]);
  const float inv2tau2 = 0.5f / (tau * tau);
  const float sig2 = 0.999f * 0.999f;
  const float t0 = times[0];

  const float c0 = sig2 + 1e-4f;
  const float isc0 = 1.0f / sqrtf(c0);

  float u[4], v[4];
#pragma unroll
  for (int c = 0; c < 4; ++c) {
    const int d = c * 64 + j;
    const float dt = times[d] - t0;
    float cv = sig2 * __expf(-dt * dt * inv2tau2);
    if (d == 0) cv = c0;
    u[c] = cv * isc0;
    v[c] = (d == 0) ? 0.0f : u[c];
  }

#pragma unroll
  for (int p = 0; p < 4; ++p) {
    for (int kk = 0; kk < 64; ++kk) {
      const float uk = __shfl(u[p], kk);
      const float vk = __shfl(v[p], kk);
      const float rho = vk * __builtin_amdgcn_rcpf(uk);
      const float om = fmaxf(1.0f - rho * rho, 1e-12f);
      const float s = __builtin_amdgcn_rsqf(om);
      const float sr = s * rho;

      float up[4];
#pragma unroll
      for (int c = 0; c < 4; ++c) {
        if (c >= p) {
          const float uc = u[c], vc = v[c];
          up[c] = s * uc - sr * vc;
          v[c]  = s * vc - sr * uc;
          const float val = (c > p || j >= kk) ? up[c] : 0.0f;
          panel[(c - p) * 64 + j][kk] = f2bf(val);
        }
      }
#pragma unroll
      for (int c = 3; c >= 0; --c) {
        if (c >= p) {
          const float t = __shfl_up(up[c], 1);
          const float tail = (c > p) ? __shfl(up[c - 1], 63) : 0.0f;
          u[c] = (j == 0) ? tail : t;
        }
      }
    }
    __syncthreads();
    const int rpt = 256 - 64 * p;
    const int rsub = j >> 4, cp = (j & 15) * 4;
    for (int i0 = 0; i0 < rpt; i0 += 4) {
      const int pr = i0 + rsub;
      short4v vv = *(const short4v*)&panel[pr][cp];
      *(short4v*)&Lbf[((size_t)(p * 64 + pr) << 8) + p * 64 + cp] = vv;
    }
    __syncthreads();
  }
}

// ---------------------------------------------------------------------------
// Stage B: z GEMM via bf16 MFMA. Block = (l, bs-tile of 16) -> 1024 blocks.
// eps tile staged through LDS (coalesced float4 reads, converted once,
// shared by all 4 waves). Wave w owns u in [64w,64w+64) => K <= 64(w+1).
// Output Z[bs][t][l] bf16.
// ---------------------------------------------------------------------------
__global__ __launch_bounds__(256) void k_zgemm(
    const float* __restrict__ eps, const __hip_bfloat16* __restrict__ Lcbf_,
    __hip_bfloat16* __restrict__ Zg)
{
  __shared__ __align__(16) short E[16][264];
  const int bi = blockIdx.x;
  const int l = bi & 7, bs0 = (bi >> 3) * 16;
  const int tid = threadIdx.x, w = tid >> 6, lane = tid & 63;
  const int n = lane & 15, q = lane >> 4;
  const short* Lb = (const short*)Lcbf_ + (size_t)l * T_ * T_;

  // stage eps[bs0+row][l][:] -> E[row][:] bf16, coalesced
  {
    const int row = tid >> 4, c16 = (tid & 15) * 16;
    const float* src = eps + ((size_t)(bs0 + row) * L_ + l) * T_ + c16;
    short4v o0, o1, o2, o3;
#pragma unroll
    for (int g = 0; g < 4; ++g) {
      float4v f = *(const float4v*)(src + g * 4);
      short4v* o = (g == 0) ? &o0 : (g == 1) ? &o1 : (g == 2) ? &o2 : &o3;
#pragma unroll
      for (int jj = 0; jj < 4; ++jj) (*o)[jj] = f2bf(f[jj]);
    }
    *(short4v*)&E[row][c16]      = o0;
    *(short4v*)&E[row][c16 + 4]  = o1;
    *(short4v*)&E[row][c16 + 8]  = o2;
    *(short4v*)&E[row][c16 + 12] = o3;
  }
  __syncthreads();

  float4v acc[4];
#pragma unroll
  for (int mt = 0; mt < 4; ++mt) acc[mt] = (float4v){0.f, 0.f, 0.f, 0.f};

  const int bs = bs0 + n;
  const int kend = (w + 1) * 64;
  for (int k0 = 0; k0 < kend; k0 += 32) {
    short8 s = *(const short8*)&E[n][k0 + q * 8];
    short8 afr[4];
#pragma unroll
    for (int mt = 0; mt < 4; ++mt) {
      const int u = w * 64 + mt * 16 + n;
      afr[mt] = *(const short8*)&Lb[((size_t)u << 8) + k0 + q * 8];
    }
#pragma unroll
    for (int mt = 0; mt < 4; ++mt)
      acc[mt] = __builtin_amdgcn_mfma_f32_16x16x32_bf16(afr[mt], s, acc[mt], 0, 0, 0);
  }
#pragma unroll
  for (int mt = 0; mt < 4; ++mt) {
#pragma unroll
    for (int r = 0; r < 4; ++r) {
      const int u = w * 64 + mt * 16 + q * 4 + r;
      Zg[((size_t)bs << 11) + (u << 3) + l] = __float2bfloat16(acc[mt][r]);
    }
  }
}

// ---------------------------------------------------------------------------
// Stages C-F fused: one block per (b,s). D-columns partitioned across waves
// (2 col-tiles each). h-values for the wave's two tiles are interleaved in
// LDS (sc perm, matching W2Tp rows) so both are written with ONE b32 store.
// mi loops unrolled by 2 (VGPR headroom at the (256,4) cap, no spill).
// ---------------------------------------------------------------------------
__global__ __launch_bounds__(256, 4) void k_decode(
    const float* __restrict__ X, const __hip_bfloat16* __restrict__ Zg,
    const __hip_bfloat16* __restrict__ W1T, const float* __restrict__ b1,
    const __hip_bfloat16* __restrict__ W2Tp, const float* __restrict__ b2,
    const float* __restrict__ log_R, float* __restrict__ ll)
{
  __shared__ __align__(16) short Zt[256][8];
  __shared__ __align__(16) __hip_bfloat16 hS[128][136];
  __shared__ float redbuf[4];

  const int bs = blockIdx.x;
  const int b = bs >> 6;
  const int tid = threadIdx.x;
  const int w = tid >> 6, lane = tid & 63;
  const int n = lane & 15, q = lane >> 4;
  const short* Zs = (const short*)Zg;
  const short* W1s = (const short*)W1T;
  const short* W2s = (const short*)W2Tp;

  *(short8*)&Zt[tid][0] = *(const short8*)&Zs[((size_t)bs << 11) + tid * 8];

  float sLR = log_R[lane] + log_R[lane + 64];
#pragma unroll
  for (int off = 32; off >= 1; off >>= 1) sLR += __shfl_xor(sLR, off);

  const int d0 = n * 8 + 2 * w;
  float invr2[2], b22[2], b12[2];
#pragma unroll
  for (int jj = 0; jj < 2; ++jj) {
    invr2[jj] = expf(-log_R[d0 + jj]);
    b22[jj] = b2[d0 + jj];
    b12[jj] = b1[(2 * w + jj) * 16 + n];
  }

  const short8 zero8 = {0, 0, 0, 0, 0, 0, 0, 0};
  short8 w1f[2];
  short8 bfr[2][4];
#pragma unroll
  for (int jj = 0; jj < 2; ++jj) {
    const int c = (2 * w + jj) * 16 + n;
    short8 v = zero8;
    if (q == 0) v = *(const short8*)&W1s[(size_t)c * L_];
    w1f[jj] = v;
#pragma unroll
    for (int ks = 0; ks < 4; ++ks)
      bfr[jj][ks] = *(const short8*)&W2s[(size_t)c * H_ + ks * 32 + q * 8];
  }

  float qsum = 0.0f;
  __syncthreads();   // Zt ready

#pragma unroll 1
  for (int half = 0; half < 2; ++half) {
    // --- h-phase: all 128 rows of this half, wave's 32 (interleaved) cols ---
#pragma unroll 2
    for (int mi = 0; mi < 8; ++mi) {
      short8 zf = zero8;
      if (q == 0) zf = *(const short8*)&Zt[half * 128 + mi * 16 + n][0];
      float4v c0 = __builtin_amdgcn_mfma_f32_16x16x32_bf16(zf, w1f[0], (float4v){0.f,0.f,0.f,0.f}, 0, 0, 0);
      float4v c1 = __builtin_amdgcn_mfma_f32_16x16x32_bf16(zf, w1f[1], (float4v){0.f,0.f,0.f,0.f}, 0, 0, 0);
#pragma unroll
      for (int r = 0; r < 4; ++r) {
        float a0 = c0[r] + b12[0];
        float e0v = __expf(2.f * a0);
        float h0 = 1.f - 2.f / (e0v + 1.f);
        float a1 = c1[r] + b12[1];
        float e1v = __expf(2.f * a1);
        float h1 = 1.f - 2.f / (e1v + 1.f);
        // pack tiles p=0,1 at sc = 32w+2n (+p): one b32 store
        unsigned pk = (unsigned)(unsigned short)f2bf(h0) |
                      ((unsigned)(unsigned short)f2bf(h1) << 16);
        ((unsigned*)&hS[mi * 16 + q * 4 + r][0])[16 * w + n] = pk;
      }
    }
    __syncthreads();
    // --- mu-phase + epilogue: wave's 2 col-tiles, all rows ---
#pragma unroll 2
    for (int mi = 0; mi < 8; ++mi) {
      short8 af[4];
#pragma unroll
      for (int ks = 0; ks < 4; ++ks)
        af[ks] = *(const short8*)&hS[mi * 16 + n][ks * 32 + q * 8];
      float4v acc0 = (float4v){0.f, 0.f, 0.f, 0.f};
      float4v acc1 = (float4v){0.f, 0.f, 0.f, 0.f};
#pragma unroll
      for (int ks = 0; ks < 4; ++ks) {
        acc0 = __builtin_amdgcn_mfma_f32_16x16x32_bf16(af[ks], bfr[0][ks], acc0, 0, 0, 0);
        acc1 = __builtin_amdgcn_mfma_f32_16x16x32_bf16(af[ks], bfr[1][ks], acc1, 0, 0, 0);
      }
#pragma unroll
      for (int r = 0; r < 4; ++r) {
        const int t = half * 128 + mi * 16 + q * 4 + r;
        const float2 xv = *(const float2*)(X + (((size_t)b << 8) + t) * D_ + d0);
        float diff0 = xv.x - (acc0[r] + b22[0]);
        float diff1 = xv.y - (acc1[r] + b22[1]);
        qsum += diff0 * diff0 * invr2[0] + diff1 * diff1 * invr2[1];
      }
    }
    __syncthreads();
  }

#pragma unroll
  for (int off = 32; off >= 1; off >>= 1) qsum += __shfl_xor(qsum, off);
  if (lane == 0) redbuf[w] = qsum;
  __syncthreads();
  if (tid == 0) {
    float Q = redbuf[0] + redbuf[1] + redbuf[2] + redbuf[3];
    float log_norm = 0.5f * (sLR + (float)D_ * 1.8378770664093453f);
    ll[bs] = -0.5f * Q - (float)T_ * log_norm;
  }
}

// ---------------------------------------------------------------------------
// Final: nll[b] = -(logsumexp_s(ll) - log S). One wave per b.
// ---------------------------------------------------------------------------
__global__ __launch_bounds__(64) void k_lse(
    const float* __restrict__ ll, float* __restrict__ out)
{
  const int b = blockIdx.x;
  const int s = threadIdx.x;
  float v = ll[b * 64 + s];
  float m = v;
#pragma unroll
  for (int off = 32; off >= 1; off >>= 1) m = fmaxf(m, __shfl_xor(m, off));
  float e = __expf(v - m);
#pragma unroll
  for (int off = 32; off >= 1; off >>= 1) e += __shfl_xor(e, off);
  if (s == 0) out[b] = -(m + __logf(e) - 4.1588830833596715f);
}

extern "C" void kernel_launch(void* const* d_in, const int* in_sizes, int n_in,
                              void* d_out, int out_size, void* d_ws, size_t ws_size,
                              hipStream_t stream) {
  const float* X        = (const float*)d_in[0];
  const float* times    = (const float*)d_in[1];
  const float* log_taus = (const float*)d_in[2];
  const float* log_R    = (const float*)d_in[3];
  const float* W1       = (const float*)d_in[4];
  const float* b1       = (const float*)d_in[5];
  const float* W2       = (const float*)d_in[6];
  const float* b2       = (const float*)d_in[7];
  const float* eps      = (const float*)d_in[8];
  float* out = (float*)d_out;

  char* ws = (char*)d_ws;
  __hip_bfloat16* Lcbf = (__hip_bfloat16*)(ws);                // 1 MiB bf16 [L][T][T]
  __hip_bfloat16* Zg   = (__hip_bfloat16*)(ws + 1048576);      // 8 MiB bf16 [BS][T][L]
  float* ll            = (float*)(ws + 9437184);               // 8 KiB
  __hip_bfloat16* W2Tp = (__hip_bfloat16*)(ws + 9445376);      // 32 KiB
  __hip_bfloat16* W1T  = (__hip_bfloat16*)(ws + 9478144);      // 2 KiB

  hipLaunchKernelGGL(k_chol_prep, dim3(72),   dim3(64),  0, stream,
                     times, log_taus, Lcbf, W1, W2, W1T, W2Tp);
  hipLaunchKernelGGL(k_zgemm,     dim3(1024), dim3(256), 0, stream, eps, Lcbf, Zg);
  hipLaunchKernelGGL(k_decode,    dim3(2048), dim3(256), 0, stream, X, Zg, W1T, b1, W2Tp, b2, log_R, ll);
  hipLaunchKernelGGL(k_lse,       dim3(32),   dim3(64),  0, stream, ll, out);
}

// Round 8
// 187.677 us; speedup vs baseline: 1.1324x; 1.1324x over previous
//
#include <hip/hip_runtime.h>
#include <hip/hip_bf16.h>
#include <math.h>

#define B_ 32
#define S_ 64
#define T_ 256
#define L_ 8
#define D_ 128
#define H_ 128

typedef __attribute__((ext_vector_type(8))) short short8;
typedef __attribute__((ext_vector_type(4))) short short4v;
typedef __attribute__((ext_vector_type(4))) float float4v;

__device__ __forceinline__ short f2bf(float x) {
  __hip_bfloat16 h = __float2bfloat16(x);
  return *reinterpret_cast<short*>(&h);
}

// ---------------------------------------------------------------------------
// Stage A (+prep merged): blocks 0-7 run the Toeplitz-Schur Cholesky (one
// wave per latent l, 256-step serial chain, LDS column panel flushed as
// coalesced rows; flush covers exactly the triangular region zgemm reads).
// Blocks 8-71 convert weights:
//   W1T[h][l]
//   W2T[c][h] with column perm c = nt*16+n <-> d = n*8+nt (decode epilogue
//   X-vectorization). NO h-interleave (R7's sc perm regressed -> reverted).
// ---------------------------------------------------------------------------
__global__ __launch_bounds__(64) void k_chol_prep(
    const float* __restrict__ times, const float* __restrict__ log_taus,
    __hip_bfloat16* __restrict__ Lcbf_,
    const float* __restrict__ W1, const float* __restrict__ W2,
    __hip_bfloat16* __restrict__ W1T, __hip_bfloat16* __restrict__ W2T)
{
  __shared__ short panel[256][68];
  const int bi = blockIdx.x;
  const int j = threadIdx.x;

  if (bi >= 8) {
    const int base = (bi - 8) * 64 + j;          // 0..4095
    for (int idx = base; idx < H_ * D_; idx += 4096) {
      const int cc = idx >> 7, h = idx & 127;
      const int n = cc & 15, nt = cc >> 4;
      const int d = n * 8 + nt;
      W2T[(size_t)cc * H_ + h] = __float2bfloat16(W2[(size_t)h * D_ + d]);
    }
    for (int idx = base; idx < L_ * H_; idx += 4096) {
      const int li = idx >> 7, h = idx & 127;
      W1T[(size_t)h * L_ + li] = __float2bfloat16(W1[idx]);
    }
    return;
  }

  const int l = bi;
  short* Lbf = (short*)Lcbf_ + (size_t)l * T_ * T_;

  const float tau = expf(log_taus[l]);
  const float inv2tau2 = 0.5f / (tau * tau);
  const float sig2 = 0.999f * 0.999f;
  const float t0 = times[0];

  const float c0 = sig2 + 1e-4f;
  const float isc0 = 1.0f / sqrtf(c0);

  float u[4], v[4];
#pragma unroll
  for (int c = 0; c < 4; ++c) {
    const int d = c * 64 + j;
    const float dt = times[d] - t0;
    float cv = sig2 * __expf(-dt * dt * inv2tau2);
    if (d == 0) cv = c0;
    u[c] = cv * isc0;
    v[c] = (d == 0) ? 0.0f : u[c];
  }

#pragma unroll
  for (int p = 0; p < 4; ++p) {
    for (int kk = 0; kk < 64; ++kk) {
      const float uk = __shfl(u[p], kk);
      const float vk = __shfl(v[p], kk);
      const float rho = vk * __builtin_amdgcn_rcpf(uk);
      const float om = fmaxf(1.0f - rho * rho, 1e-12f);
      const float s = __builtin_amdgcn_rsqf(om);
      const float sr = s * rho;

      float up[4];
#pragma unroll
      for (int c = 0; c < 4; ++c) {
        if (c >= p) {
          const float uc = u[c], vc = v[c];
          up[c] = s * uc - sr * vc;
          v[c]  = s * vc - sr * uc;
          const float val = (c > p || j >= kk) ? up[c] : 0.0f;
          panel[(c - p) * 64 + j][kk] = f2bf(val);
        }
      }
#pragma unroll
      for (int c = 3; c >= 0; --c) {
        if (c >= p) {
          const float t = __shfl_up(up[c], 1);
          const float tail = (c > p) ? __shfl(up[c - 1], 63) : 0.0f;
          u[c] = (j == 0) ? tail : t;
        }
      }
    }
    __syncthreads();
    const int rpt = 256 - 64 * p;
    const int rsub = j >> 4, cp = (j & 15) * 4;
    for (int i0 = 0; i0 < rpt; i0 += 4) {
      const int pr = i0 + rsub;
      short4v vv = *(const short4v*)&panel[pr][cp];
      *(short4v*)&Lbf[((size_t)(p * 64 + pr) << 8) + p * 64 + cp] = vv;
    }
    __syncthreads();
  }
}

// ---------------------------------------------------------------------------
// Stage B: z GEMM via bf16 MFMA. Block = (l, bs-tile of 16) -> 1024 blocks.
// eps tile staged through LDS (coalesced float4 reads, converted once,
// shared by all 4 waves). Wave w owns u in [64w,64w+64) => K <= 64(w+1).
// Output Z[bs][t][l] bf16.
// ---------------------------------------------------------------------------
__global__ __launch_bounds__(256) void k_zgemm(
    const float* __restrict__ eps, const __hip_bfloat16* __restrict__ Lcbf_,
    __hip_bfloat16* __restrict__ Zg)
{
  __shared__ __align__(16) short E[16][264];
  const int bi = blockIdx.x;
  const int l = bi & 7, bs0 = (bi >> 3) * 16;
  const int tid = threadIdx.x, w = tid >> 6, lane = tid & 63;
  const int n = lane & 15, q = lane >> 4;
  const short* Lb = (const short*)Lcbf_ + (size_t)l * T_ * T_;

  {
    const int row = tid >> 4, c16 = (tid & 15) * 16;
    const float* src = eps + ((size_t)(bs0 + row) * L_ + l) * T_ + c16;
    short4v o0, o1, o2, o3;
#pragma unroll
    for (int g = 0; g < 4; ++g) {
      float4v f = *(const float4v*)(src + g * 4);
      short4v* o = (g == 0) ? &o0 : (g == 1) ? &o1 : (g == 2) ? &o2 : &o3;
#pragma unroll
      for (int jj = 0; jj < 4; ++jj) (*o)[jj] = f2bf(f[jj]);
    }
    *(short4v*)&E[row][c16]      = o0;
    *(short4v*)&E[row][c16 + 4]  = o1;
    *(short4v*)&E[row][c16 + 8]  = o2;
    *(short4v*)&E[row][c16 + 12] = o3;
  }
  __syncthreads();

  float4v acc[4];
#pragma unroll
  for (int mt = 0; mt < 4; ++mt) acc[mt] = (float4v){0.f, 0.f, 0.f, 0.f};

  const int bs = bs0 + n;
  const int kend = (w + 1) * 64;
  for (int k0 = 0; k0 < kend; k0 += 32) {
    short8 s = *(const short8*)&E[n][k0 + q * 8];
    short8 afr[4];
#pragma unroll
    for (int mt = 0; mt < 4; ++mt) {
      const int u = w * 64 + mt * 16 + n;
      afr[mt] = *(const short8*)&Lb[((size_t)u << 8) + k0 + q * 8];
    }
#pragma unroll
    for (int mt = 0; mt < 4; ++mt)
      acc[mt] = __builtin_amdgcn_mfma_f32_16x16x32_bf16(afr[mt], s, acc[mt], 0, 0, 0);
  }
#pragma unroll
  for (int mt = 0; mt < 4; ++mt) {
#pragma unroll
    for (int r = 0; r < 4; ++r) {
      const int u = w * 64 + mt * 16 + q * 4 + r;
      Zg[((size_t)bs << 11) + (u << 3) + l] = __float2bfloat16(acc[mt][r]);
    }
  }
}

// ---------------------------------------------------------------------------
// Stages C-F fused (R6 known-good structure): one block per (b,s). D-columns
// partitioned across waves (2 col-tiles each). half/mi loops NOT unrolled
// (pragma unroll 1) -> no scratch spill at the (256,4) VGPR cap.
// Only change vs R6: joint reciprocal for each tanh pair (1 rcp + 3 mul
// instead of 2 rcp; exact limit at overflow since rcp(inf)=0 -> h=1).
// ---------------------------------------------------------------------------
__global__ __launch_bounds__(256, 4) void k_decode(
    const float* __restrict__ X, const __hip_bfloat16* __restrict__ Zg,
    const __hip_bfloat16* __restrict__ W1T, const float* __restrict__ b1,
    const __hip_bfloat16* __restrict__ W2T, const float* __restrict__ b2,
    const float* __restrict__ log_R, float* __restrict__ ll)
{
  __shared__ __align__(16) short Zt[256][8];
  __shared__ __align__(16) __hip_bfloat16 hS[128][136];
  __shared__ float redbuf[4];

  const int bs = blockIdx.x;
  const int b = bs >> 6;
  const int tid = threadIdx.x;
  const int w = tid >> 6, lane = tid & 63;
  const int n = lane & 15, q = lane >> 4;
  const short* Zs = (const short*)Zg;
  const short* W1s = (const short*)W1T;
  const short* W2s = (const short*)W2T;

  *(short8*)&Zt[tid][0] = *(const short8*)&Zs[((size_t)bs << 11) + tid * 8];

  float sLR = log_R[lane] + log_R[lane + 64];
#pragma unroll
  for (int off = 32; off >= 1; off >>= 1) sLR += __shfl_xor(sLR, off);

  const int d0 = n * 8 + 2 * w;
  float invr2[2], b22[2], b12[2];
#pragma unroll
  for (int jj = 0; jj < 2; ++jj) {
    invr2[jj] = expf(-log_R[d0 + jj]);
    b22[jj] = b2[d0 + jj];
    b12[jj] = b1[(2 * w + jj) * 16 + n];
  }

  const short8 zero8 = {0, 0, 0, 0, 0, 0, 0, 0};
  short8 w1f[2];
  short8 bfr[2][4];
#pragma unroll
  for (int jj = 0; jj < 2; ++jj) {
    const int c = (2 * w + jj) * 16 + n;
    short8 v = zero8;
    if (q == 0) v = *(const short8*)&W1s[(size_t)c * L_];
    w1f[jj] = v;
#pragma unroll
    for (int ks = 0; ks < 4; ++ks)
      bfr[jj][ks] = *(const short8*)&W2s[(size_t)c * H_ + ks * 32 + q * 8];
  }

  float qsum = 0.0f;
  __syncthreads();   // Zt ready

#pragma unroll 1
  for (int half = 0; half < 2; ++half) {
    // --- h-phase: all 128 rows of this half, wave's 32 cols ---
#pragma unroll 1
    for (int mi = 0; mi < 8; ++mi) {
      short8 zf = zero8;
      if (q == 0) zf = *(const short8*)&Zt[half * 128 + mi * 16 + n][0];
      float4v c0 = __builtin_amdgcn_mfma_f32_16x16x32_bf16(zf, w1f[0], (float4v){0.f,0.f,0.f,0.f}, 0, 0, 0);
      float4v c1 = __builtin_amdgcn_mfma_f32_16x16x32_bf16(zf, w1f[1], (float4v){0.f,0.f,0.f,0.f}, 0, 0, 0);
#pragma unroll
      for (int r = 0; r < 4; ++r) {
        float a0 = c0[r] + b12[0];
        float a1 = c1[r] + b12[1];
        float p0 = __expf(2.f * a0) + 1.f;
        float p1 = __expf(2.f * a1) + 1.f;
        float rj = __builtin_amdgcn_rcpf(p0 * p1);     // joint reciprocal
        float h0 = 1.f - 2.f * p1 * rj;
        float h1 = 1.f - 2.f * p0 * rj;
        hS[mi * 16 + q * 4 + r][(2 * w) * 16 + n] = __float2bfloat16(h0);
        hS[mi * 16 + q * 4 + r][(2 * w + 1) * 16 + n] = __float2bfloat16(h1);
      }
    }
    __syncthreads();
    // --- mu-phase + epilogue: wave's 2 col-tiles, all rows ---
#pragma unroll 1
    for (int mi = 0; mi < 8; ++mi) {
      short8 af[4];
#pragma unroll
      for (int ks = 0; ks < 4; ++ks)
        af[ks] = *(const short8*)&hS[mi * 16 + n][ks * 32 + q * 8];
      float4v acc0 = (float4v){0.f, 0.f, 0.f, 0.f};
      float4v acc1 = (float4v){0.f, 0.f, 0.f, 0.f};
#pragma unroll
      for (int ks = 0; ks < 4; ++ks) {
        acc0 = __builtin_amdgcn_mfma_f32_16x16x32_bf16(af[ks], bfr[0][ks], acc0, 0, 0, 0);
        acc1 = __builtin_amdgcn_mfma_f32_16x16x32_bf16(af[ks], bfr[1][ks], acc1, 0, 0, 0);
      }
#pragma unroll
      for (int r = 0; r < 4; ++r) {
        const int t = half * 128 + mi * 16 + q * 4 + r;
        const float2 xv = *(const float2*)(X + (((size_t)b << 8) + t) * D_ + d0);
        float diff0 = xv.x - (acc0[r] + b22[0]);
        float diff1 = xv.y - (acc1[r] + b22[1]);
        qsum += diff0 * diff0 * invr2[0] + diff1 * diff1 * invr2[1];
      }
    }
    __syncthreads();
  }

#pragma unroll
  for (int off = 32; off >= 1; off >>= 1) qsum += __shfl_xor(qsum, off);
  if (lane == 0) redbuf[w] = qsum;
  __syncthreads();
  if (tid == 0) {
    float Q = redbuf[0] + redbuf[1] + redbuf[2] + redbuf[3];
    float log_norm = 0.5f * (sLR + (float)D_ * 1.8378770664093453f);
    ll[bs] = -0.5f * Q - (float)T_ * log_norm;
  }
}

// ---------------------------------------------------------------------------
// Final: nll[b] = -(logsumexp_s(ll) - log S). One wave per b.
// ---------------------------------------------------------------------------
__global__ __launch_bounds__(64) void k_lse(
    const float* __restrict__ ll, float* __restrict__ out)
{
  const int b = blockIdx.x;
  const int s = threadIdx.x;
  float v = ll[b * 64 + s];
  float m = v;
#pragma unroll
  for (int off = 32; off >= 1; off >>= 1) m = fmaxf(m, __shfl_xor(m, off));
  float e = __expf(v - m);
#pragma unroll
  for (int off = 32; off >= 1; off >>= 1) e += __shfl_xor(e, off);
  if (s == 0) out[b] = -(m + __logf(e) - 4.1588830833596715f);
}

extern "C" void kernel_launch(void* const* d_in, const int* in_sizes, int n_in,
                              void* d_out, int out_size, void* d_ws, size_t ws_size,
                              hipStream_t stream) {
  const float* X        = (const float*)d_in[0];
  const float* times    = (const float*)d_in[1];
  const float* log_taus = (const float*)d_in[2];
  const float* log_R    = (const float*)d_in[3];
  const float* W1       = (const float*)d_in[4];
  const float* b1       = (const float*)d_in[5];
  const float* W2       = (const float*)d_in[6];
  const float* b2       = (const float*)d_in[7];
  const float* eps      = (const float*)d_in[8];
  float* out = (float*)d_out;

  char* ws = (char*)d_ws;
  __hip_bfloat16* Lcbf = (__hip_bfloat16*)(ws);                // 1 MiB bf16 [L][T][T]
  __hip_bfloat16* Zg   = (__hip_bfloat16*)(ws + 1048576);      // 8 MiB bf16 [BS][T][L]
  float* ll            = (float*)(ws + 9437184);               // 8 KiB
  __hip_bfloat16* W2T  = (__hip_bfloat16*)(ws + 9445376);      // 32 KiB
  __hip_bfloat16* W1T  = (__hip_bfloat16*)(ws + 9478144);      // 2 KiB

  hipLaunchKernelGGL(k_chol_prep, dim3(72),   dim3(64),  0, stream,
                     times, log_taus, Lcbf, W1, W2, W1T, W2T);
  hipLaunchKernelGGL(k_zgemm,     dim3(1024), dim3(256), 0, stream, eps, Lcbf, Zg);
  hipLaunchKernelGGL(k_decode,    dim3(2048), dim3(256), 0, stream, X, Zg, W1T, b1, W2T, b2, log_R, ll);
  hipLaunchKernelGGL(k_lse,       dim3(32),   dim3(64),  0, stream, ll, out);
}

// Round 9
// 180.923 us; speedup vs baseline: 1.1747x; 1.0373x over previous
//
#include <hip/hip_runtime.h>
#include <hip/hip_bf16.h>
#include <math.h>

#define B_ 32
#define S_ 64
#define T_ 256
#define L_ 8
#define D_ 128
#define H_ 128

typedef __attribute__((ext_vector_type(8))) short short8;
typedef __attribute__((ext_vector_type(4))) short short4v;
typedef __attribute__((ext_vector_type(4))) float float4v;

__device__ __forceinline__ short f2bf(float x) {
  __hip_bfloat16 h = __float2bfloat16(x);
  return *reinterpret_cast<short*>(&h);
}

// lane-uniform broadcast of lane `sl` (sl must be wave-uniform): v_readlane
__device__ __forceinline__ float rdlane(float x, int sl) {
  return __int_as_float(__builtin_amdgcn_readlane(__float_as_int(x), sl));
}
// shift down by one lane across the whole wave (DPP wave_shr:1, ~2 cyc);
// lane 0 receives `tailv` (old-value path, bound_ctrl=0)
__device__ __forceinline__ float dpp_shr1(float x, float tailv) {
  int r = __builtin_amdgcn_update_dpp(__float_as_int(tailv), __float_as_int(x),
                                      0x138, 0xF, 0xF, false);
  return __int_as_float(r);
}

// ---------------------------------------------------------------------------
// Stage A (+prep merged): blocks 0-7: Toeplitz-Schur Cholesky, one wave per
// latent l. Serial 256-step chain; cross-lane ops implemented with
// v_readlane (uniform broadcast) and DPP wave_shr:1 (shift) instead of
// LDS-pipe shuffles -> ~4x shorter dependency chain. Columns buffered in an
// LDS panel, flushed as coalesced rows (covers exactly zgemm's read region).
// Blocks 8-71: weight conversion W1T[h][l], W2T[c][h] (c = nt*16+n <-> d =
// n*8+nt for decode epilogue X-vectorization).
// ---------------------------------------------------------------------------
__global__ __launch_bounds__(64) void k_chol_prep(
    const float* __restrict__ times, const float* __restrict__ log_taus,
    __hip_bfloat16* __restrict__ Lcbf_,
    const float* __restrict__ W1, const float* __restrict__ W2,
    __hip_bfloat16* __restrict__ W1T, __hip_bfloat16* __restrict__ W2T)
{
  __shared__ short panel[256][68];
  const int bi = blockIdx.x;
  const int j = threadIdx.x;

  if (bi >= 8) {
    const int base = (bi - 8) * 64 + j;          // 0..4095
    for (int idx = base; idx < H_ * D_; idx += 4096) {
      const int cc = idx >> 7, h = idx & 127;
      const int n = cc & 15, nt = cc >> 4;
      const int d = n * 8 + nt;
      W2T[(size_t)cc * H_ + h] = __float2bfloat16(W2[(size_t)h * D_ + d]);
    }
    for (int idx = base; idx < L_ * H_; idx += 4096) {
      const int li = idx >> 7, h = idx & 127;
      W1T[(size_t)h * L_ + li] = __float2bfloat16(W1[idx]);
    }
    return;
  }

  const int l = bi;
  short* Lbf = (short*)Lcbf_ + (size_t)l * T_ * T_;

  const float tau = expf(log_taus[l]);
  const float inv2tau2 = 0.5f / (tau * tau);
  const float sig2 = 0.999f * 0.999f;
  const float t0 = times[0];

  const float c0 = sig2 + 1e-4f;
  const float isc0 = 1.0f / sqrtf(c0);

  float u[4], v[4];
#pragma unroll
  for (int c = 0; c < 4; ++c) {
    const int d = c * 64 + j;
    const float dt = times[d] - t0;
    float cv = sig2 * __expf(-dt * dt * inv2tau2);
    if (d == 0) cv = c0;
    u[c] = cv * isc0;
    v[c] = (d == 0) ? 0.0f : u[c];
  }

#pragma unroll
  for (int p = 0; p < 4; ++p) {
    for (int kk = 0; kk < 64; ++kk) {
      const float uk = rdlane(u[p], kk);
      const float vk = rdlane(v[p], kk);
      const float rho = vk * __builtin_amdgcn_rcpf(uk);
      const float om = fmaxf(1.0f - rho * rho, 1e-12f);
      const float s = __builtin_amdgcn_rsqf(om);
      const float sr = s * rho;

      float up[4];
#pragma unroll
      for (int c = 0; c < 4; ++c) {
        if (c >= p) {
          const float uc = u[c], vc = v[c];
          up[c] = s * uc - sr * vc;
          v[c]  = s * vc - sr * uc;
          const float val = (c > p || j >= kk) ? up[c] : 0.0f;
          panel[(c - p) * 64 + j][kk] = f2bf(val);
        }
      }
      // shift u down one row: DPP wave_shr:1, lane0 <- tail of chunk below
#pragma unroll
      for (int c = 3; c >= 0; --c) {
        if (c >= p) {
          const float tail = (c > p) ? rdlane(up[c - 1], 63) : 0.0f;
          u[c] = dpp_shr1(up[c], tail);
        }
      }
    }
    __syncthreads();
    const int rpt = 256 - 64 * p;
    const int rsub = j >> 4, cp = (j & 15) * 4;
    for (int i0 = 0; i0 < rpt; i0 += 4) {
      const int pr = i0 + rsub;
      short4v vv = *(const short4v*)&panel[pr][cp];
      *(short4v*)&Lbf[((size_t)(p * 64 + pr) << 8) + p * 64 + cp] = vv;
    }
    __syncthreads();
  }
}

// ---------------------------------------------------------------------------
// Stage B: z GEMM via bf16 MFMA. Block = (l, bs-tile of 16) -> 1024 blocks.
// eps tile staged through LDS. Wave w owns u in [64w,64w+64) => K <= 64(w+1).
// Output Z[bs][t][l] bf16.
// ---------------------------------------------------------------------------
__global__ __launch_bounds__(256) void k_zgemm(
    const float* __restrict__ eps, const __hip_bfloat16* __restrict__ Lcbf_,
    __hip_bfloat16* __restrict__ Zg)
{
  __shared__ __align__(16) short E[16][264];
  const int bi = blockIdx.x;
  const int l = bi & 7, bs0 = (bi >> 3) * 16;
  const int tid = threadIdx.x, w = tid >> 6, lane = tid & 63;
  const int n = lane & 15, q = lane >> 4;
  const short* Lb = (const short*)Lcbf_ + (size_t)l * T_ * T_;

  {
    const int row = tid >> 4, c16 = (tid & 15) * 16;
    const float* src = eps + ((size_t)(bs0 + row) * L_ + l) * T_ + c16;
    short4v o0, o1, o2, o3;
#pragma unroll
    for (int g = 0; g < 4; ++g) {
      float4v f = *(const float4v*)(src + g * 4);
      short4v* o = (g == 0) ? &o0 : (g == 1) ? &o1 : (g == 2) ? &o2 : &o3;
#pragma unroll
      for (int jj = 0; jj < 4; ++jj) (*o)[jj] = f2bf(f[jj]);
    }
    *(short4v*)&E[row][c16]      = o0;
    *(short4v*)&E[row][c16 + 4]  = o1;
    *(short4v*)&E[row][c16 + 8]  = o2;
    *(short4v*)&E[row][c16 + 12] = o3;
  }
  __syncthreads();

  float4v acc[4];
#pragma unroll
  for (int mt = 0; mt < 4; ++mt) acc[mt] = (float4v){0.f, 0.f, 0.f, 0.f};

  const int bs = bs0 + n;
  const int kend = (w + 1) * 64;
  for (int k0 = 0; k0 < kend; k0 += 32) {
    short8 s = *(const short8*)&E[n][k0 + q * 8];
    short8 afr[4];
#pragma unroll
    for (int mt = 0; mt < 4; ++mt) {
      const int u = w * 64 + mt * 16 + n;
      afr[mt] = *(const short8*)&Lb[((size_t)u << 8) + k0 + q * 8];
    }
#pragma unroll
    for (int mt = 0; mt < 4; ++mt)
      acc[mt] = __builtin_amdgcn_mfma_f32_16x16x32_bf16(afr[mt], s, acc[mt], 0, 0, 0);
  }
#pragma unroll
  for (int mt = 0; mt < 4; ++mt) {
#pragma unroll
    for (int r = 0; r < 4; ++r) {
      const int u = w * 64 + mt * 16 + q * 4 + r;
      Zg[((size_t)bs << 11) + (u << 3) + l] = __float2bfloat16(acc[mt][r]);
    }
  }
}

// ---------------------------------------------------------------------------
// Stages C-F fused (R8 known-good): one block per (b,s). D-columns
// partitioned across waves (2 col-tiles each); unroll 1 -> no spill at the
// (256,4) cap; joint reciprocal for each tanh pair.
// ---------------------------------------------------------------------------
__global__ __launch_bounds__(256, 4) void k_decode(
    const float* __restrict__ X, const __hip_bfloat16* __restrict__ Zg,
    const __hip_bfloat16* __restrict__ W1T, const float* __restrict__ b1,
    const __hip_bfloat16* __restrict__ W2T, const float* __restrict__ b2,
    const float* __restrict__ log_R, float* __restrict__ ll)
{
  __shared__ __align__(16) short Zt[256][8];
  __shared__ __align__(16) __hip_bfloat16 hS[128][136];
  __shared__ float redbuf[4];

  const int bs = blockIdx.x;
  const int b = bs >> 6;
  const int tid = threadIdx.x;
  const int w = tid >> 6, lane = tid & 63;
  const int n = lane & 15, q = lane >> 4;
  const short* Zs = (const short*)Zg;
  const short* W1s = (const short*)W1T;
  const short* W2s = (const short*)W2T;

  *(short8*)&Zt[tid][0] = *(const short8*)&Zs[((size_t)bs << 11) + tid * 8];

  float sLR = log_R[lane] + log_R[lane + 64];
#pragma unroll
  for (int off = 32; off >= 1; off >>= 1) sLR += __shfl_xor(sLR, off);

  const int d0 = n * 8 + 2 * w;
  float invr2[2], b22[2], b12[2];
#pragma unroll
  for (int jj = 0; jj < 2; ++jj) {
    invr2[jj] = expf(-log_R[d0 + jj]);
    b22[jj] = b2[d0 + jj];
    b12[jj] = b1[(2 * w + jj) * 16 + n];
  }

  const short8 zero8 = {0, 0, 0, 0, 0, 0, 0, 0};
  short8 w1f[2];
  short8 bfr[2][4];
#pragma unroll
  for (int jj = 0; jj < 2; ++jj) {
    const int c = (2 * w + jj) * 16 + n;
    short8 v = zero8;
    if (q == 0) v = *(const short8*)&W1s[(size_t)c * L_];
    w1f[jj] = v;
#pragma unroll
    for (int ks = 0; ks < 4; ++ks)
      bfr[jj][ks] = *(const short8*)&W2s[(size_t)c * H_ + ks * 32 + q * 8];
  }

  float qsum = 0.0f;
  __syncthreads();   // Zt ready

#pragma unroll 1
  for (int half = 0; half < 2; ++half) {
#pragma unroll 1
    for (int mi = 0; mi < 8; ++mi) {
      short8 zf = zero8;
      if (q == 0) zf = *(const short8*)&Zt[half * 128 + mi * 16 + n][0];
      float4v c0 = __builtin_amdgcn_mfma_f32_16x16x32_bf16(zf, w1f[0], (float4v){0.f,0.f,0.f,0.f}, 0, 0, 0);
      float4v c1 = __builtin_amdgcn_mfma_f32_16x16x32_bf16(zf, w1f[1], (float4v){0.f,0.f,0.f,0.f}, 0, 0, 0);
#pragma unroll
      for (int r = 0; r < 4; ++r) {
        float a0 = c0[r] + b12[0];
        float a1 = c1[r] + b12[1];
        float p0 = __expf(2.f * a0) + 1.f;
        float p1 = __expf(2.f * a1) + 1.f;
        float rj = __builtin_amdgcn_rcpf(p0 * p1);
        float h0 = 1.f - 2.f * p1 * rj;
        float h1 = 1.f - 2.f * p0 * rj;
        hS[mi * 16 + q * 4 + r][(2 * w) * 16 + n] = __float2bfloat16(h0);
        hS[mi * 16 + q * 4 + r][(2 * w + 1) * 16 + n] = __float2bfloat16(h1);
      }
    }
    __syncthreads();
#pragma unroll 1
    for (int mi = 0; mi < 8; ++mi) {
      short8 af[4];
#pragma unroll
      for (int ks = 0; ks < 4; ++ks)
        af[ks] = *(const short8*)&hS[mi * 16 + n][ks * 32 + q * 8];
      float4v acc0 = (float4v){0.f, 0.f, 0.f, 0.f};
      float4v acc1 = (float4v){0.f, 0.f, 0.f, 0.f};
#pragma unroll
      for (int ks = 0; ks < 4; ++ks) {
        acc0 = __builtin_amdgcn_mfma_f32_16x16x32_bf16(af[ks], bfr[0][ks], acc0, 0, 0, 0);
        acc1 = __builtin_amdgcn_mfma_f32_16x16x32_bf16(af[ks], bfr[1][ks], acc1, 0, 0, 0);
      }
#pragma unroll
      for (int r = 0; r < 4; ++r) {
        const int t = half * 128 + mi * 16 + q * 4 + r;
        const float2 xv = *(const float2*)(X + (((size_t)b << 8) + t) * D_ + d0);
        float diff0 = xv.x - (acc0[r] + b22[0]);
        float diff1 = xv.y - (acc1[r] + b22[1]);
        qsum += diff0 * diff0 * invr2[0] + diff1 * diff1 * invr2[1];
      }
    }
    __syncthreads();
  }

#pragma unroll
  for (int off = 32; off >= 1; off >>= 1) qsum += __shfl_xor(qsum, off);
  if (lane == 0) redbuf[w] = qsum;
  __syncthreads();
  if (tid == 0) {
    float Q = redbuf[0] + redbuf[1] + redbuf[2] + redbuf[3];
    float log_norm = 0.5f * (sLR + (float)D_ * 1.8378770664093453f);
    ll[bs] = -0.5f * Q - (float)T_ * log_norm;
  }
}

// ---------------------------------------------------------------------------
// Final: nll[b] = -(logsumexp_s(ll) - log S). One wave per b.
// ---------------------------------------------------------------------------
__global__ __launch_bounds__(64) void k_lse(
    const float* __restrict__ ll, float* __restrict__ out)
{
  const int b = blockIdx.x;
  const int s = threadIdx.x;
  float v = ll[b * 64 + s];
  float m = v;
#pragma unroll
  for (int off = 32; off >= 1; off >>= 1) m = fmaxf(m, __shfl_xor(m, off));
  float e = __expf(v - m);
#pragma unroll
  for (int off = 32; off >= 1; off >>= 1) e += __shfl_xor(e, off);
  if (s == 0) out[b] = -(m + __logf(e) - 4.1588830833596715f);
}

extern "C" void kernel_launch(void* const* d_in, const int* in_sizes, int n_in,
                              void* d_out, int out_size, void* d_ws, size_t ws_size,
                              hipStream_t stream) {
  const float* X        = (const float*)d_in[0];
  const float* times    = (const float*)d_in[1];
  const float* log_taus = (const float*)d_in[2];
  const float* log_R    = (const float*)d_in[3];
  const float* W1       = (const float*)d_in[4];
  const float* b1       = (const float*)d_in[5];
  const float* W2       = (const float*)d_in[6];
  const float* b2       = (const float*)d_in[7];
  const float* eps      = (const float*)d_in[8];
  float* out = (float*)d_out;

  char* ws = (char*)d_ws;
  __hip_bfloat16* Lcbf = (__hip_bfloat16*)(ws);                // 1 MiB bf16 [L][T][T]
  __hip_bfloat16* Zg   = (__hip_bfloat16*)(ws + 1048576);      // 8 MiB bf16 [BS][T][L]
  float* ll            = (float*)(ws + 9437184);               // 8 KiB
  __hip_bfloat16* W2T  = (__hip_bfloat16*)(ws + 9445376);      // 32 KiB
  __hip_bfloat16* W1T  = (__hip_bfloat16*)(ws + 9478144);      // 2 KiB

  hipLaunchKernelGGL(k_chol_prep, dim3(72),   dim3(64),  0, stream,
                     times, log_taus, Lcbf, W1, W2, W1T, W2T);
  hipLaunchKernelGGL(k_zgemm,     dim3(1024), dim3(256), 0, stream, eps, Lcbf, Zg);
  hipLaunchKernelGGL(k_decode,    dim3(2048), dim3(256), 0, stream, X, Zg, W1T, b1, W2T, b2, log_R, ll);
  hipLaunchKernelGGL(k_lse,       dim3(32),   dim3(64),  0, stream, ll, out);
}

// Round 10
// 173.480 us; speedup vs baseline: 1.2251x; 1.0429x over previous
//
#include <hip/hip_runtime.h>
#include <hip/hip_bf16.h>
#include <math.h>

#define B_ 32
#define S_ 64
#define T_ 256
#define L_ 8
#define D_ 128
#define H_ 128

typedef __attribute__((ext_vector_type(8))) short short8;
typedef __attribute__((ext_vector_type(4))) short short4v;
typedef __attribute__((ext_vector_type(4))) float float4v;

__device__ __forceinline__ short f2bf(float x) {
  __hip_bfloat16 h = __float2bfloat16(x);
  return *reinterpret_cast<short*>(&h);
}

// lane-uniform broadcast of lane `sl` (sl must be wave-uniform): v_readlane
__device__ __forceinline__ float rdlane(float x, int sl) {
  return __int_as_float(__builtin_amdgcn_readlane(__float_as_int(x), sl));
}
// shift down by one lane across the whole wave (DPP wave_shr:1, ~2 cyc);
// lane 0 receives `tailv` (old-value path, bound_ctrl=0)
__device__ __forceinline__ float dpp_shr1(float x, float tailv) {
  int r = __builtin_amdgcn_update_dpp(__float_as_int(tailv), __float_as_int(x),
                                      0x138, 0xF, 0xF, false);
  return __int_as_float(r);
}

// ---------------------------------------------------------------------------
// Stage A (+prep merged): blocks 0-7: Toeplitz-Schur Cholesky, one wave per
// latent l (readlane broadcast + DPP wave_shr shift; LDS panel flushed as
// coalesced rows covering exactly zgemm's triangular read region).
// Blocks 8-71: weight conversion W1T[h][l], W2T[c][h] (c=nt*16+n <-> d=n*8+nt).
// ---------------------------------------------------------------------------
__global__ __launch_bounds__(64) void k_chol_prep(
    const float* __restrict__ times, const float* __restrict__ log_taus,
    __hip_bfloat16* __restrict__ Lcbf_,
    const float* __restrict__ W1, const float* __restrict__ W2,
    __hip_bfloat16* __restrict__ W1T, __hip_bfloat16* __restrict__ W2T)
{
  __shared__ short panel[256][68];
  const int bi = blockIdx.x;
  const int j = threadIdx.x;

  if (bi >= 8) {
    const int base = (bi - 8) * 64 + j;          // 0..4095
    for (int idx = base; idx < H_ * D_; idx += 4096) {
      const int cc = idx >> 7, h = idx & 127;
      const int n = cc & 15, nt = cc >> 4;
      const int d = n * 8 + nt;
      W2T[(size_t)cc * H_ + h] = __float2bfloat16(W2[(size_t)h * D_ + d]);
    }
    for (int idx = base; idx < L_ * H_; idx += 4096) {
      const int li = idx >> 7, h = idx & 127;
      W1T[(size_t)h * L_ + li] = __float2bfloat16(W1[idx]);
    }
    return;
  }

  const int l = bi;
  short* Lbf = (short*)Lcbf_ + (size_t)l * T_ * T_;

  const float tau = expf(log_taus[l]);
  const float inv2tau2 = 0.5f / (tau * tau);
  const float sig2 = 0.999f * 0.999f;
  const float t0 = times[0];

  const float c0 = sig2 + 1e-4f;
  const float isc0 = 1.0f / sqrtf(c0);

  float u[4], v[4];
#pragma unroll
  for (int c = 0; c < 4; ++c) {
    const int d = c * 64 + j;
    const float dt = times[d] - t0;
    float cv = sig2 * __expf(-dt * dt * inv2tau2);
    if (d == 0) cv = c0;
    u[c] = cv * isc0;
    v[c] = (d == 0) ? 0.0f : u[c];
  }

#pragma unroll
  for (int p = 0; p < 4; ++p) {
    for (int kk = 0; kk < 64; ++kk) {
      const float uk = rdlane(u[p], kk);
      const float vk = rdlane(v[p], kk);
      const float rho = vk * __builtin_amdgcn_rcpf(uk);
      const float om = fmaxf(1.0f - rho * rho, 1e-12f);
      const float s = __builtin_amdgcn_rsqf(om);
      const float sr = s * rho;

      float up[4];
#pragma unroll
      for (int c = 0; c < 4; ++c) {
        if (c >= p) {
          const float uc = u[c], vc = v[c];
          up[c] = s * uc - sr * vc;
          v[c]  = s * vc - sr * uc;
          const float val = (c > p || j >= kk) ? up[c] : 0.0f;
          panel[(c - p) * 64 + j][kk] = f2bf(val);
        }
      }
#pragma unroll
      for (int c = 3; c >= 0; --c) {
        if (c >= p) {
          const float tail = (c > p) ? rdlane(up[c - 1], 63) : 0.0f;
          u[c] = dpp_shr1(up[c], tail);
        }
      }
    }
    __syncthreads();
    const int rpt = 256 - 64 * p;
    const int rsub = j >> 4, cp = (j & 15) * 4;
    for (int i0 = 0; i0 < rpt; i0 += 4) {
      const int pr = i0 + rsub;
      short4v vv = *(const short4v*)&panel[pr][cp];
      *(short4v*)&Lbf[((size_t)(p * 64 + pr) << 8) + p * 64 + cp] = vv;
    }
    __syncthreads();
  }
}

// ---------------------------------------------------------------------------
// Stage B: z GEMM via bf16 MFMA. Block = (l, bs-tile of 64) -> 256 blocks
// (64-wide tiles amortize L2-side L reads 4x vs 16-wide; R3/R4 A/B showed
// ~15 us swing). eps staged once through LDS (coalesced float4, converted
// once per element). Wave w owns u in [64w,64w+64) => K <= 64(w+1)
// (triangular skip). Output Z[bs][t][l] bf16.
// ---------------------------------------------------------------------------
__global__ __launch_bounds__(256) void k_zgemm(
    const float* __restrict__ eps, const __hip_bfloat16* __restrict__ Lcbf_,
    __hip_bfloat16* __restrict__ Zg)
{
  __shared__ __align__(16) short E[64][264];
  const int bi = blockIdx.x;
  const int l = bi & 7, bs0 = (bi >> 3) * 64;
  const int tid = threadIdx.x, w = tid >> 6, lane = tid & 63;
  const int n = lane & 15, q = lane >> 4;
  const short* Lb = (const short*)Lcbf_ + (size_t)l * T_ * T_;

  // stage eps[bs0+row][l][:] -> E[row][:] bf16; each thread: 64 floats
  {
    const int row = tid >> 2, seg = (tid & 3) * 64;
    const float* src = eps + ((size_t)(bs0 + row) * L_ + l) * T_ + seg;
#pragma unroll
    for (int g = 0; g < 16; ++g) {
      float4v f = *(const float4v*)(src + g * 4);
      short4v o;
#pragma unroll
      for (int jj = 0; jj < 4; ++jj) o[jj] = f2bf(f[jj]);
      *(short4v*)&E[row][seg + g * 4] = o;
    }
  }
  __syncthreads();

  float4v acc[4][4];
#pragma unroll
  for (int mt = 0; mt < 4; ++mt)
#pragma unroll
    for (int nt = 0; nt < 4; ++nt) acc[mt][nt] = (float4v){0.f, 0.f, 0.f, 0.f};

  const int kend = (w + 1) * 64;
  for (int k0 = 0; k0 < kend; k0 += 32) {
    short8 bfrg[4], afr[4];
#pragma unroll
    for (int nt = 0; nt < 4; ++nt)
      bfrg[nt] = *(const short8*)&E[nt * 16 + n][k0 + q * 8];
#pragma unroll
    for (int mt = 0; mt < 4; ++mt) {
      const int u = w * 64 + mt * 16 + n;
      afr[mt] = *(const short8*)&Lb[((size_t)u << 8) + k0 + q * 8];
    }
#pragma unroll
    for (int mt = 0; mt < 4; ++mt)
#pragma unroll
      for (int nt = 0; nt < 4; ++nt)
        acc[mt][nt] = __builtin_amdgcn_mfma_f32_16x16x32_bf16(afr[mt], bfrg[nt], acc[mt][nt], 0, 0, 0);
  }
#pragma unroll
  for (int mt = 0; mt < 4; ++mt)
#pragma unroll
    for (int nt = 0; nt < 4; ++nt) {
      const int bs = bs0 + nt * 16 + n;
#pragma unroll
      for (int r = 0; r < 4; ++r) {
        const int u = w * 64 + mt * 16 + q * 4 + r;
        Zg[((size_t)bs << 11) + (u << 3) + l] = __float2bfloat16(acc[mt][nt][r]);
      }
    }
}

// ---------------------------------------------------------------------------
// Stages C-F fused (R8/R9 known-good): one block per (b,s). D-columns
// partitioned across waves (2 col-tiles each); unroll 1 -> no spill at the
// (256,4) cap; joint reciprocal per tanh pair.
// ---------------------------------------------------------------------------
__global__ __launch_bounds__(256, 4) void k_decode(
    const float* __restrict__ X, const __hip_bfloat16* __restrict__ Zg,
    const __hip_bfloat16* __restrict__ W1T, const float* __restrict__ b1,
    const __hip_bfloat16* __restrict__ W2T, const float* __restrict__ b2,
    const float* __restrict__ log_R, float* __restrict__ ll)
{
  __shared__ __align__(16) short Zt[256][8];
  __shared__ __align__(16) __hip_bfloat16 hS[128][136];
  __shared__ float redbuf[4];

  const int bs = blockIdx.x;
  const int b = bs >> 6;
  const int tid = threadIdx.x;
  const int w = tid >> 6, lane = tid & 63;
  const int n = lane & 15, q = lane >> 4;
  const short* Zs = (const short*)Zg;
  const short* W1s = (const short*)W1T;
  const short* W2s = (const short*)W2T;

  *(short8*)&Zt[tid][0] = *(const short8*)&Zs[((size_t)bs << 11) + tid * 8];

  float sLR = log_R[lane] + log_R[lane + 64];
#pragma unroll
  for (int off = 32; off >= 1; off >>= 1) sLR += __shfl_xor(sLR, off);

  const int d0 = n * 8 + 2 * w;
  float invr2[2], b22[2], b12[2];
#pragma unroll
  for (int jj = 0; jj < 2; ++jj) {
    invr2[jj] = expf(-log_R[d0 + jj]);
    b22[jj] = b2[d0 + jj];
    b12[jj] = b1[(2 * w + jj) * 16 + n];
  }

  const short8 zero8 = {0, 0, 0, 0, 0, 0, 0, 0};
  short8 w1f[2];
  short8 bfr[2][4];
#pragma unroll
  for (int jj = 0; jj < 2; ++jj) {
    const int c = (2 * w + jj) * 16 + n;
    short8 v = zero8;
    if (q == 0) v = *(const short8*)&W1s[(size_t)c * L_];
    w1f[jj] = v;
#pragma unroll
    for (int ks = 0; ks < 4; ++ks)
      bfr[jj][ks] = *(const short8*)&W2s[(size_t)c * H_ + ks * 32 + q * 8];
  }

  float qsum = 0.0f;
  __syncthreads();   // Zt ready

#pragma unroll 1
  for (int half = 0; half < 2; ++half) {
#pragma unroll 1
    for (int mi = 0; mi < 8; ++mi) {
      short8 zf = zero8;
      if (q == 0) zf = *(const short8*)&Zt[half * 128 + mi * 16 + n][0];
      float4v c0 = __builtin_amdgcn_mfma_f32_16x16x32_bf16(zf, w1f[0], (float4v){0.f,0.f,0.f,0.f}, 0, 0, 0);
      float4v c1 = __builtin_amdgcn_mfma_f32_16x16x32_bf16(zf, w1f[1], (float4v){0.f,0.f,0.f,0.f}, 0, 0, 0);
#pragma unroll
      for (int r = 0; r < 4; ++r) {
        float a0 = c0[r] + b12[0];
        float a1 = c1[r] + b12[1];
        float p0 = __expf(2.f * a0) + 1.f;
        float p1 = __expf(2.f * a1) + 1.f;
        float rj = __builtin_amdgcn_rcpf(p0 * p1);
        float h0 = 1.f - 2.f * p1 * rj;
        float h1 = 1.f - 2.f * p0 * rj;
        hS[mi * 16 + q * 4 + r][(2 * w) * 16 + n] = __float2bfloat16(h0);
        hS[mi * 16 + q * 4 + r][(2 * w + 1) * 16 + n] = __float2bfloat16(h1);
      }
    }
    __syncthreads();
#pragma unroll 1
    for (int mi = 0; mi < 8; ++mi) {
      short8 af[4];
#pragma unroll
      for (int ks = 0; ks < 4; ++ks)
        af[ks] = *(const short8*)&hS[mi * 16 + n][ks * 32 + q * 8];
      float4v acc0 = (float4v){0.f, 0.f, 0.f, 0.f};
      float4v acc1 = (float4v){0.f, 0.f, 0.f, 0.f};
#pragma unroll
      for (int ks = 0; ks < 4; ++ks) {
        acc0 = __builtin_amdgcn_mfma_f32_16x16x32_bf16(af[ks], bfr[0][ks], acc0, 0, 0, 0);
        acc1 = __builtin_amdgcn_mfma_f32_16x16x32_bf16(af[ks], bfr[1][ks], acc1, 0, 0, 0);
      }
#pragma unroll
      for (int r = 0; r < 4; ++r) {
        const int t = half * 128 + mi * 16 + q * 4 + r;
        const float2 xv = *(const float2*)(X + (((size_t)b << 8) + t) * D_ + d0);
        float diff0 = xv.x - (acc0[r] + b22[0]);
        float diff1 = xv.y - (acc1[r] + b22[1]);
        qsum += diff0 * diff0 * invr2[0] + diff1 * diff1 * invr2[1];
      }
    }
    __syncthreads();
  }

#pragma unroll
  for (int off = 32; off >= 1; off >>= 1) qsum += __shfl_xor(qsum, off);
  if (lane == 0) redbuf[w] = qsum;
  __syncthreads();
  if (tid == 0) {
    float Q = redbuf[0] + redbuf[1] + redbuf[2] + redbuf[3];
    float log_norm = 0.5f * (sLR + (float)D_ * 1.8378770664093453f);
    ll[bs] = -0.5f * Q - (float)T_ * log_norm;
  }
}

// ---------------------------------------------------------------------------
// Final: nll[b] = -(logsumexp_s(ll) - log S). One wave per b.
// ---------------------------------------------------------------------------
__global__ __launch_bounds__(64) void k_lse(
    const float* __restrict__ ll, float* __restrict__ out)
{
  const int b = blockIdx.x;
  const int s = threadIdx.x;
  float v = ll[b * 64 + s];
  float m = v;
#pragma unroll
  for (int off = 32; off >= 1; off >>= 1) m = fmaxf(m, __shfl_xor(m, off));
  float e = __expf(v - m);
#pragma unroll
  for (int off = 32; off >= 1; off >>= 1) e += __shfl_xor(e, off);
  if (s == 0) out[b] = -(m + __logf(e) - 4.1588830833596715f);
}

extern "C" void kernel_launch(void* const* d_in, const int* in_sizes, int n_in,
                              void* d_out, int out_size, void* d_ws, size_t ws_size,
                              hipStream_t stream) {
  const float* X        = (const float*)d_in[0];
  const float* times    = (const float*)d_in[1];
  const float* log_taus = (const float*)d_in[2];
  const float* log_R    = (const float*)d_in[3];
  const float* W1       = (const float*)d_in[4];
  const float* b1       = (const float*)d_in[5];
  const float* W2       = (const float*)d_in[6];
  const float* b2       = (const float*)d_in[7];
  const float* eps      = (const float*)d_in[8];
  float* out = (float*)d_out;

  char* ws = (char*)d_ws;
  __hip_bfloat16* Lcbf = (__hip_bfloat16*)(ws);                // 1 MiB bf16 [L][T][T]
  __hip_bfloat16* Zg   = (__hip_bfloat16*)(ws + 1048576);      // 8 MiB bf16 [BS][T][L]
  float* ll            = (float*)(ws + 9437184);               // 8 KiB
  __hip_bfloat16* W2T  = (__hip_bfloat16*)(ws + 9445376);      // 32 KiB
  __hip_bfloat16* W1T  = (__hip_bfloat16*)(ws + 9478144);      // 2 KiB

  hipLaunchKernelGGL(k_chol_prep, dim3(72),   dim3(64),  0, stream,
                     times, log_taus, Lcbf, W1, W2, W1T, W2T);
  hipLaunchKernelGGL(k_zgemm,     dim3(256),  dim3(256), 0, stream, eps, Lcbf, Zg);
  hipLaunchKernelGGL(k_decode,    dim3(2048), dim3(256), 0, stream, X, Zg, W1T, b1, W2T, b2, log_R, ll);
  hipLaunchKernelGGL(k_lse,       dim3(32),   dim3(64),  0, stream, ll, out);
}